// Round 1
// baseline (236.030 us; speedup 1.0000x reference)
//
#include <hip/hip_runtime.h>

#define NP 8732
#define NO 16
#define BLK 256

// One block per batch row: match priors<->boxes, compute CE for all priors,
// loc L1 for positives, and hard-negative top-K sum via LDS radix-select.
__global__ __launch_bounds__(BLK) void mbox_row_kernel(
    const float* __restrict__ plocs,    // [B,P,4]
    const float* __restrict__ pscores,  // [B,P,2]
    const float* __restrict__ boxes,    // [B,O,4] cxcy
    const float* __restrict__ priors,   // [P,4]  cxcy
    float* __restrict__ loc_out,        // [B]
    float* __restrict__ conf_out,       // [B]
    int*   __restrict__ npos_out)       // [B]
{
    const int b    = blockIdx.x;
    const int tid  = threadIdx.x;
    const int lane = tid & 63;
    const int wv   = tid >> 6;

    __shared__ float         s_ce[NP];       // phase A: ov_per_prior; phase C: ce_neg
    __shared__ unsigned char s_obj[NP];      // obj_per_prior (<16)
    __shared__ float s_bcw[NO][4];           // boxes cxcy
    __shared__ float s_bxy[NO][4];           // boxes corners
    __shared__ float s_barea[NO];
    __shared__ float s_redv[NO * 4];
    __shared__ int   s_redi[NO * 4];
    __shared__ int   s_bestp[NO];
    __shared__ unsigned int s_hist[16];
    __shared__ unsigned int s_state[2];      // prefix, k
    __shared__ int   s_ribuf[4];

    // ---- load boxes, precompute corners & areas ----
    if (tid < NO * 4) ((float*)s_bcw)[tid] = boxes[(size_t)b * NO * 4 + tid];
    __syncthreads();
    if (tid < NO) {
        float cx = s_bcw[tid][0], cy = s_bcw[tid][1];
        float w  = s_bcw[tid][2], h  = s_bcw[tid][3];
        float x0 = cx - w * 0.5f, y0 = cy - h * 0.5f;
        float x1 = cx + w * 0.5f, y1 = cy + h * 0.5f;
        s_bxy[tid][0] = x0; s_bxy[tid][1] = y0;
        s_bxy[tid][2] = x1; s_bxy[tid][3] = y1;
        s_barea[tid] = (x1 - x0) * (y1 - y0);
    }
    __syncthreads();

    // ---- phase A: IoU, per-prior argmax over objects, per-object argmax over priors ----
    float tbv[NO]; int tbp[NO];
#pragma unroll
    for (int o = 0; o < NO; o++) { tbv[o] = -1.0f; tbp[o] = 0; }

    for (int p = tid; p < NP; p += BLK) {
        float4 pr = ((const float4*)priors)[p];
        float px0 = pr.x - pr.z * 0.5f, py0 = pr.y - pr.w * 0.5f;
        float px1 = pr.x + pr.z * 0.5f, py1 = pr.y + pr.w * 0.5f;
        float areab = (px1 - px0) * (py1 - py0);
        float bestv = -1.0f; int besto = 0;
#pragma unroll
        for (int o = 0; o < NO; o++) {
            float ix0 = fmaxf(s_bxy[o][0], px0);
            float iy0 = fmaxf(s_bxy[o][1], py0);
            float ix1 = fminf(s_bxy[o][2], px1);
            float iy1 = fminf(s_bxy[o][3], py1);
            float iw = fmaxf(ix1 - ix0, 0.0f);
            float ih = fmaxf(iy1 - iy0, 0.0f);
            float inter = iw * ih;
            float iou = inter / (s_barea[o] + areab - inter);
            if (iou > bestv) { bestv = iou; besto = o; }        // first-wins over o
            if (iou > tbv[o]) { tbv[o] = iou; tbp[o] = p; }     // first-wins over p (ascending)
        }
        s_ce[p]  = bestv;
        s_obj[p] = (unsigned char)besto;
    }

    // reduce per-object best prior across the block (prefer larger val, then smaller idx)
#pragma unroll
    for (int o = 0; o < NO; o++) {
        float v = tbv[o]; int i = tbp[o];
        for (int off = 32; off; off >>= 1) {
            float v2 = __shfl_down(v, off, 64);
            int   i2 = __shfl_down(i, off, 64);
            if (v2 > v || (v2 == v && i2 < i)) { v = v2; i = i2; }
        }
        if (lane == 0) { s_redv[o * 4 + wv] = v; s_redi[o * 4 + wv] = i; }
    }
    __syncthreads();
    if (tid < NO) {
        float v = s_redv[tid * 4]; int i = s_redi[tid * 4];
#pragma unroll
        for (int w = 1; w < 4; w++) {
            float v2 = s_redv[tid * 4 + w]; int i2 = s_redi[tid * 4 + w];
            if (v2 > v || (v2 == v && i2 < i)) { v = v2; i = i2; }
        }
        s_bestp[tid] = i;
    }
    __syncthreads();
    // forced assignment (serial ascending: last o wins on duplicate priors)
    if (tid == 0) {
#pragma unroll
        for (int o = 0; o < NO; o++) {
            int bp = s_bestp[o];
            s_obj[bp] = (unsigned char)o;
            s_ce[bp]  = 1.0f;
        }
    }
    __syncthreads();

    // ---- phase C: CE for all priors, loc L1 for positives, build ce_neg in LDS ----
    float loc_sum = 0.0f, conf_pos = 0.0f; int np = 0;
    const float2* sc2 = (const float2*)(pscores + (size_t)b * NP * 2);
    const float4* pl4 = (const float4*)(plocs  + (size_t)b * NP * 4);
    for (int p = tid; p < NP; p += BLK) {
        float ov = s_ce[p];
        bool pos = (ov >= 0.5f);
        float2 s = sc2[p];
        float m  = fmaxf(s.x, s.y);
        float lse = m + logf(expf(s.x - m) + expf(s.y - m));
        float ce = lse - (pos ? s.y : s.x);
        if (pos) {
            np++;
            conf_pos += ce;
            int o = s_obj[p];
            float4 pr = ((const float4*)priors)[p];
            float gx = (s_bcw[o][0] - pr.x) / (pr.z / 10.0f);
            float gy = (s_bcw[o][1] - pr.y) / (pr.w / 10.0f);
            float gw = logf(s_bcw[o][2] / pr.z) * 5.0f;
            float gh = logf(s_bcw[o][3] / pr.w) * 5.0f;
            float4 pl = pl4[p];
            loc_sum += fabsf(pl.x - gx) + fabsf(pl.y - gy)
                     + fabsf(pl.z - gw) + fabsf(pl.w - gh);
            s_ce[p] = 0.0f;   // positives contribute 0 to ce_neg (matches jnp.where)
        } else {
            s_ce[p] = ce;
        }
    }

    // reduce n_pos (needed for K before the select)
    int npw = np;
    for (int off = 32; off; off >>= 1) npw += __shfl_down(npw, off, 64);
    if (lane == 0) s_ribuf[wv] = npw;
    __syncthreads();   // also makes all s_ce writes visible
    const int n_pos = s_ribuf[0] + s_ribuf[1] + s_ribuf[2] + s_ribuf[3];

    // ---- phase D: radix-select K-th largest of s_ce (all values >= 0) ----
    const int K = 3 * n_pos;
    const bool selAll = (K >= NP);
    float t = 0.0f;
    if (!selAll) {
        if (tid == 0) { s_state[0] = 0u; s_state[1] = (unsigned)K; }
        for (int shift = 28; shift >= 0; shift -= 4) {
            __syncthreads();
            if (tid < 16) s_hist[tid] = 0u;
            __syncthreads();
            unsigned int prefix = s_state[0];
            unsigned int maskhi = (shift == 28) ? 0u : (0xFFFFFFFFu << (shift + 4));
            for (int p = tid; p < NP; p += BLK) {
                unsigned int u = __float_as_uint(s_ce[p]);
                if ((u & maskhi) == prefix)
                    atomicAdd(&s_hist[(u >> shift) & 15u], 1u);
            }
            __syncthreads();
            if (tid == 0) {
                unsigned int kk = s_state[1];
                int d = 15;
                for (; d > 0; d--) { if (kk <= s_hist[d]) break; kk -= s_hist[d]; }
                s_state[0] = prefix | ((unsigned)d << shift);
                s_state[1] = kk;
            }
        }
        __syncthreads();
        t = __uint_as_float(s_state[0]);
    }

    // sum of top-K = sum(v > t) + (K - cnt_gt) * t   (exact under ties)
    float sgt = 0.0f; int cgt = 0;
    for (int p = tid; p < NP; p += BLK) {
        float v = s_ce[p];
        if (selAll || v > t) { sgt += v; cgt++; }
    }

    // ---- final block reduction of (sgt, conf_pos, loc_sum, cgt) ----
    float a = sgt, c = conf_pos, l = loc_sum; int g = cgt;
    for (int off = 32; off; off >>= 1) {
        a += __shfl_down(a, off, 64);
        c += __shfl_down(c, off, 64);
        l += __shfl_down(l, off, 64);
        g += __shfl_down(g, off, 64);
    }
    __syncthreads();
    if (lane == 0) {
        s_redv[wv] = a; s_redv[4 + wv] = c; s_redv[8 + wv] = l; s_redi[wv] = g;
    }
    __syncthreads();
    if (tid == 0) {
        float sa = s_redv[0] + s_redv[1] + s_redv[2] + s_redv[3];
        float sc = s_redv[4] + s_redv[5] + s_redv[6] + s_redv[7];
        float sl = s_redv[8] + s_redv[9] + s_redv[10] + s_redv[11];
        int   sg = s_redi[0] + s_redi[1] + s_redi[2] + s_redi[3];
        float conf_hn = selAll ? sa : (sa + (float)(K - sg) * t);
        conf_out[b] = sc + conf_hn;
        loc_out[b]  = sl;
        npos_out[b] = n_pos;
    }
}

__global__ __launch_bounds__(BLK) void mbox_finalize_kernel(
    const float* __restrict__ loc_in,
    const float* __restrict__ conf_in,
    const int*   __restrict__ npos_in,
    int B, float* __restrict__ out)
{
    __shared__ float sl[4], sc[4];
    __shared__ int   si[4];
    int tid = threadIdx.x, lane = tid & 63, wv = tid >> 6;
    float l = 0.0f, c = 0.0f; int n = 0;
    for (int i = tid; i < B; i += BLK) { l += loc_in[i]; c += conf_in[i]; n += npos_in[i]; }
    for (int off = 32; off; off >>= 1) {
        l += __shfl_down(l, off, 64);
        c += __shfl_down(c, off, 64);
        n += __shfl_down(n, off, 64);
    }
    if (lane == 0) { sl[wv] = l; sc[wv] = c; si[wv] = n; }
    __syncthreads();
    if (tid == 0) {
        float tl = sl[0] + sl[1] + sl[2] + sl[3];
        float tc = sc[0] + sc[1] + sc[2] + sc[3];
        int   tn = si[0] + si[1] + si[2] + si[3];
        float fn = (float)tn;
        out[0] = tc / fn + tl / (fn * 4.0f);
    }
}

extern "C" void kernel_launch(void* const* d_in, const int* in_sizes, int n_in,
                              void* d_out, int out_size, void* d_ws, size_t ws_size,
                              hipStream_t stream) {
    const float* plocs   = (const float*)d_in[0];
    const float* pscores = (const float*)d_in[1];
    const float* boxes   = (const float*)d_in[2];
    const float* priors  = (const float*)d_in[3];
    const int B = in_sizes[0] / (NP * 4);

    float* loc_ws  = (float*)d_ws;
    float* conf_ws = loc_ws + B;
    int*   np_ws   = (int*)(conf_ws + B);

    mbox_row_kernel<<<B, BLK, 0, stream>>>(plocs, pscores, boxes, priors,
                                           loc_ws, conf_ws, np_ws);
    mbox_finalize_kernel<<<1, BLK, 0, stream>>>(loc_ws, conf_ws, np_ws, B, (float*)d_out);
}